// Round 4
// 224.636 us; speedup vs baseline: 1.0047x; 1.0047x over previous
//
#include <hip/hip_runtime.h>
#include <hip/hip_bf16.h>

typedef __attribute__((ext_vector_type(8))) short short8;
typedef __attribute__((ext_vector_type(4))) float floatx4;

constexpr float LN_EPS = 1e-5f;
constexpr float NEG_INF_V = -1e30f;

// HW RNE packed convert via the compiler's native lowering (learn_hip m240:
// plain casts lower to v_cvt_pk_bf16_f32; hand-written asm is slower).
// Memory layout of __hip_bfloat162 is {lo16=x, hi16=y}, so as a u32:
// D[15:0] = bf16(a), D[31:16] = bf16(b).
__device__ __forceinline__ unsigned int pk2(float a, float b) {
    float2 f2; f2.x = a; f2.y = b;
    __hip_bfloat162 h2 = __float22bfloat162_rn(f2);
    unsigned int u;
    __builtin_memcpy(&u, &h2, sizeof(u));   // not bit_cast: bfloat162 isn't trivially copyable
    return u;
}
// hi/lo split of a pair: lo captures hi's rounding residual, so the 3-pass
// MFMA product error is ~2^-17. RNE == previous software RNE → bit-identical.
__device__ __forceinline__ void splitpk(float a, float b,
                                        unsigned int& H, unsigned int& L) {
    H = pk2(a, b);
    const float ha = __builtin_bit_cast(float, H << 16);
    const float hb = __builtin_bit_cast(float, H & 0xFFFF0000u);
    L = pk2(a - ha, b - hb);
}

// XOR-swizzled 64x64 bf16 LDS layout: 16B group g of row r at position g ^ (r & 7)
__device__ __forceinline__ int eoff(int r, int c) {
    return r * 64 + ((((c >> 3) ^ r) & 7) << 3) + (c & 7);
}
__device__ __forceinline__ int goff(int r, int g) {
    return r * 64 + (((g ^ r) & 7) << 3);
}

__device__ __forceinline__ float rsum16(float v) {
    v += __shfl_xor(v, 1, 64);
    v += __shfl_xor(v, 2, 64);
    v += __shfl_xor(v, 4, 64);
    v += __shfl_xor(v, 8, 64);
    return v;
}
__device__ __forceinline__ float rmax16(float v) {
    v = fmaxf(v, __shfl_xor(v, 1, 64));
    v = fmaxf(v, __shfl_xor(v, 2, 64));
    v = fmaxf(v, __shfl_xor(v, 4, 64));
    v = fmaxf(v, __shfl_xor(v, 8, 64));
    return v;
}

__global__ __launch_bounds__(256, 4)
void attn_mfma(const float* __restrict__ fi,
               const float* __restrict__ corr,
               const float* __restrict__ ln_g,
               const float* __restrict__ ln_b,
               const float* __restrict__ lw,
               const float* __restrict__ lb,
               float* __restrict__ out)
{
    // 5 x 8 KB = 40960 B -> 4 blocks/CU
    __shared__ __align__(16) unsigned short sFiH[4096], sFiL[4096]; // fi rows h/l
    __shared__ __align__(16) unsigned short sFtH[4096];             // fi^T rows, hi
    // sPH/sPL: phase 1 = C^T h/l (staged per block); phase 2 = fiC h/l; sPH phase 3 = alpha
    __shared__ __align__(16) unsigned short sPH[4096], sPL[4096];

    const int tid  = threadIdx.x;
    const int lane = tid & 63;
    const int w    = tid >> 6;
    const int n    = lane & 15;
    const int quad = lane >> 4;
    const size_t blk = blockIdx.x;

    // ---- staging: thread owns 16 elems of fi row r (wave-private stripe) ----
    const int r = tid >> 2;
    const int a = tid & 3;
    float d0 = 0.f;
    {
        const float* fb = fi + blk * 4096 + (size_t)r * 64;
        #pragma unroll
        for (int i = 0; i < 4; ++i) {
            const int c = a * 4 + 16 * i;
            float4 v   = *(const float4*)(fb + c);
            float4 w0v = *(const float4*)&lw[c];
            d0 += v.x * w0v.x + v.y * w0v.y + v.z * w0v.z + v.w * w0v.w;
            unsigned int H01, L01, H23, L23;
            splitpk(v.x, v.y, H01, L01);
            splitpk(v.z, v.w, H23, L23);
            uint2 H = {H01, H23};
            uint2 L = {L01, L23};
            *(uint2*)&sFiH[eoff(r, c)] = H;   // 8B-aligned (c%8 in {0,4})
            *(uint2*)&sFiL[eoff(r, c)] = L;
            sFtH[eoff(c + 0, r)] = (unsigned short)H01;
            sFtH[eoff(c + 1, r)] = (unsigned short)(H01 >> 16);
            sFtH[eoff(c + 2, r)] = (unsigned short)H23;
            sFtH[eoff(c + 3, r)] = (unsigned short)(H23 >> 16);
        }
        d0 += __shfl_xor(d0, 1, 64);
        d0 += __shfl_xor(d0, 2, 64);   // 4 threads of row r all hold fi[r].w0
    }
    // ---- stage C^T h/l into dead sPH/sPL (corr is L1-hot after first block) ----
    {
        const float* cb = corr + (size_t)r * 64;
        #pragma unroll
        for (int i = 0; i < 4; ++i) {
            const int c = a * 4 + 16 * i;
            float4 v = *(const float4*)(cb + c);
            unsigned int H01, L01, H23, L23;
            splitpk(v.x, v.y, H01, L01);
            splitpk(v.z, v.w, H23, L23);
            sPH[eoff(c + 0, r)] = (unsigned short)H01;   // Ct[col][row]
            sPH[eoff(c + 1, r)] = (unsigned short)(H01 >> 16);
            sPH[eoff(c + 2, r)] = (unsigned short)H23;
            sPH[eoff(c + 3, r)] = (unsigned short)(H23 >> 16);
            sPL[eoff(c + 0, r)] = (unsigned short)L01;
            sPL[eoff(c + 1, r)] = (unsigned short)(L01 >> 16);
            sPL[eoff(c + 2, r)] = (unsigned short)L23;
            sPL[eoff(c + 3, r)] = (unsigned short)(L23 >> 16);
        }
    }
    __syncthreads();   // bar1: sFi/sFt/Ct visible

    const int arow = 16 * w + n;

    // ---- M1: fiC = fi @ C (A: own-stripe sFi rows h/l; B: Ct h/l from LDS) ----
    short8 Ah[2], Al[2];
    #pragma unroll
    for (int kk = 0; kk < 2; ++kk) {
        Ah[kk] = *(const short8*)&sFiH[goff(arow, kk * 4 + quad)];
        Al[kk] = *(const short8*)&sFiL[goff(arow, kk * 4 + quad)];
    }
    floatx4 acc1[4];
    #pragma unroll
    for (int t = 0; t < 4; ++t) {
        floatx4 acc = {0.f, 0.f, 0.f, 0.f};
        const int brow = 16 * t + n;
        #pragma unroll
        for (int kk = 0; kk < 2; ++kk) {
            short8 bh = *(const short8*)&sPH[goff(brow, kk * 4 + quad)];
            short8 bl = *(const short8*)&sPL[goff(brow, kk * 4 + quad)];
            acc = __builtin_amdgcn_mfma_f32_16x16x32_bf16(Ah[kk], bh, acc, 0, 0, 0);
            acc = __builtin_amdgcn_mfma_f32_16x16x32_bf16(Al[kk], bh, acc, 0, 0, 0);
            acc = __builtin_amdgcn_mfma_f32_16x16x32_bf16(Ah[kk], bl, acc, 0, 0, 0);
        }
        acc1[t] = acc;
    }

    __syncthreads();   // bar2: all waves done reading Ct from sPH/sPL

    // fiC -> sP (wave-private rows overwrite Ct)
    #pragma unroll
    for (int t = 0; t < 4; ++t) {
        const int col = 16 * t + n;
        const int row = 16 * w + quad * 4;
        unsigned int H01, L01, H23, L23;
        splitpk(acc1[t][0], acc1[t][1], H01, L01);
        splitpk(acc1[t][2], acc1[t][3], H23, L23);
        sPH[eoff(row + 0, col)] = (unsigned short)H01;
        sPH[eoff(row + 1, col)] = (unsigned short)(H01 >> 16);
        sPH[eoff(row + 2, col)] = (unsigned short)H23;
        sPH[eoff(row + 3, col)] = (unsigned short)(H23 >> 16);
        sPL[eoff(row + 0, col)] = (unsigned short)L01;
        sPL[eoff(row + 1, col)] = (unsigned short)(L01 >> 16);
        sPL[eoff(row + 2, col)] = (unsigned short)L23;
        sPL[eoff(row + 3, col)] = (unsigned short)(L23 >> 16);
    }

    // ---- M2: beta = fiC @ fi^T (A: own sP rows, self-written; B: sFi rows) ----
    short8 PAh[2], PAl[2];
    #pragma unroll
    for (int kk = 0; kk < 2; ++kk) {
        PAh[kk] = *(const short8*)&sPH[goff(arow, kk * 4 + quad)];
        PAl[kk] = *(const short8*)&sPL[goff(arow, kk * 4 + quad)];
    }
    floatx4 acc2[4];
    #pragma unroll
    for (int t = 0; t < 4; ++t) {
        floatx4 acc = {0.f, 0.f, 0.f, 0.f};
        const int brow = 16 * t + n;
        #pragma unroll
        for (int kk = 0; kk < 2; ++kk) {
            short8 bh = *(const short8*)&sFiH[goff(brow, kk * 4 + quad)];
            short8 bl = *(const short8*)&sFiL[goff(brow, kk * 4 + quad)];
            acc = __builtin_amdgcn_mfma_f32_16x16x32_bf16(PAh[kk], bh, acc, 0, 0, 0);
            acc = __builtin_amdgcn_mfma_f32_16x16x32_bf16(PAl[kk], bh, acc, 0, 0, 0);
            acc = __builtin_amdgcn_mfma_f32_16x16x32_bf16(PAh[kk], bl, acc, 0, 0, 0);
        }
        acc2[t] = acc;
    }

    // ---- masked softmax, UNNORMALIZED (LN is scale-invariant; eps effect ~5e-5) ----
    #pragma unroll
    for (int reg = 0; reg < 4; ++reg) {
        const int row = 16 * w + quad * 4 + reg;
        float x[4];
        #pragma unroll
        for (int t = 0; t < 4; ++t) {
            x[t] = acc2[t][reg];
            if (row == 16 * t + n) x[t] = NEG_INF_V;
        }
        float m = fmaxf(fmaxf(x[0], x[1]), fmaxf(x[2], x[3]));
        m = rmax16(m);
        #pragma unroll
        for (int t = 0; t < 4; ++t) x[t] = __expf(x[t] - m);   // <= 1, no sum/divide
        const unsigned int A01 = pk2(x[0], x[1]);
        const unsigned int A23 = pk2(x[2], x[3]);
        sPH[eoff(row, 0 + n)]  = (unsigned short)A01;   // alpha reuses sPH (own rows)
        sPH[eoff(row, 16 + n)] = (unsigned short)(A01 >> 16);
        sPH[eoff(row, 32 + n)] = (unsigned short)A23;
        sPH[eoff(row, 48 + n)] = (unsigned short)(A23 >> 16);
    }

    // ---- M3: vi_unnorm = exp(beta-m) @ fi (hi-only single pass) ----
    short8 AAh[2];
    #pragma unroll
    for (int kk = 0; kk < 2; ++kk)
        AAh[kk] = *(const short8*)&sPH[goff(arow, kk * 4 + quad)];
    floatx4 acc3[4];
    #pragma unroll
    for (int t = 0; t < 4; ++t) {
        floatx4 acc = {0.f, 0.f, 0.f, 0.f};
        const int brow = 16 * t + n;
        #pragma unroll
        for (int kk = 0; kk < 2; ++kk) {
            short8 bh = *(const short8*)&sFtH[goff(brow, kk * 4 + quad)];
            acc = __builtin_amdgcn_mfma_f32_16x16x32_bf16(AAh[kk], bh, acc, 0, 0, 0);
        }
        acc3[t] = acc;
    }

    // ---- LN + ReLU + final dot + sigmoid ----
    float gv[4], bv[4], w1v[4];
    #pragma unroll
    for (int t = 0; t < 4; ++t) {
        gv[t]  = ln_g[16 * t + n];
        bv[t]  = ln_b[16 * t + n];
        w1v[t] = lw[64 + 16 * t + n];
    }
    const float bias = lb[0];
    float res[4];
    #pragma unroll
    for (int reg = 0; reg < 4; ++reg) {
        const int row16 = quad * 4 + reg;
        float s  = acc3[0][reg] + acc3[1][reg] + acc3[2][reg] + acc3[3][reg];
        float s2 = acc3[0][reg] * acc3[0][reg] + acc3[1][reg] * acc3[1][reg]
                 + acc3[2][reg] * acc3[2][reg] + acc3[3][reg] * acc3[3][reg];
        s  = rsum16(s);
        s2 = rsum16(s2);
        const float mu  = s * (1.0f / 64.0f);
        const float var = s2 * (1.0f / 64.0f) - mu * mu;
        const float rstd = __builtin_amdgcn_rsqf(var + LN_EPS);
        float dotp = 0.f;
        #pragma unroll
        for (int t = 0; t < 4; ++t) {
            float lnv = (acc3[t][reg] - mu) * rstd * gv[t] + bv[t];
            lnv = fmaxf(lnv, 0.f);
            dotp += lnv * w1v[t];
        }
        dotp = rsum16(dotp);
        const float d0row = __shfl(d0, row16 << 2, 64);
        res[reg] = __builtin_amdgcn_rcpf(1.0f + __expf(-(dotp + d0row + bias)));
    }
    if (n == 0) {
        float4 o = {res[0], res[1], res[2], res[3]};
        *(float4*)&out[blk * 64 + 16 * w + quad * 4] = o;
    }
}

extern "C" void kernel_launch(void* const* d_in, const int* in_sizes, int n_in,
                              void* d_out, int out_size, void* d_ws, size_t ws_size,
                              hipStream_t stream) {
    const float* fi   = (const float*)d_in[0];
    const float* corr = (const float*)d_in[1];
    const float* g    = (const float*)d_in[2];
    const float* b    = (const float*)d_in[3];
    const float* lw   = (const float*)d_in[4];
    const float* lb   = (const float*)d_in[5];
    float* out        = (float*)d_out;

    const int B = in_sizes[0] / 4096;
    hipLaunchKernelGGL(attn_mfma, dim3(B), dim3(256), 0, stream,
                       fi, corr, g, b, lw, lb, out);
}

// Round 5
// 214.611 us; speedup vs baseline: 1.0517x; 1.0467x over previous
//
#include <hip/hip_runtime.h>
#include <hip/hip_bf16.h>

typedef __attribute__((ext_vector_type(8))) short short8;
typedef __attribute__((ext_vector_type(4))) float floatx4;

constexpr float LN_EPS = 1e-5f;
constexpr float NEG_INF_V = -1e30f;

// ---- bf16 helpers ----
// software RNE (prep kernel only; == HW RNE)
__device__ __forceinline__ unsigned short bf16hi_sw(float x) {
    unsigned int u = __builtin_bit_cast(unsigned int, x);
    u += 0x7FFFu + ((u >> 16) & 1u);
    return (unsigned short)(u >> 16);
}
__device__ __forceinline__ float bf16f(unsigned short h) {
    unsigned int u = ((unsigned int)h) << 16;
    return __builtin_bit_cast(float, u);
}
// HW RNE packed convert (compiler lowers to v_cvt_pk_bf16_f32).
// u32: [15:0]=bf16(a), [31:16]=bf16(b)
__device__ __forceinline__ unsigned int pk2(float a, float b) {
    float2 f2; f2.x = a; f2.y = b;
    __hip_bfloat162 h2 = __float22bfloat162_rn(f2);
    unsigned int u;
    __builtin_memcpy(&u, &h2, sizeof(u));   // bfloat162 isn't trivially copyable
    return u;
}
// hi/lo split of a pair: lo captures hi's rounding residual (error ~2^-17)
__device__ __forceinline__ void splitpk(float a, float b,
                                        unsigned int& H, unsigned int& L) {
    H = pk2(a, b);
    const float ha = __builtin_bit_cast(float, H << 16);
    const float hb = __builtin_bit_cast(float, H & 0xFFFF0000u);
    L = pk2(a - ha, b - hb);
}

// byte-perm packs: lo16(A)|lo16(B)<<16  /  hi16(A)|hi16(B)<<16
__device__ __forceinline__ unsigned int permlo(unsigned int A, unsigned int B) {
    return __builtin_amdgcn_perm(B, A, 0x05040100u);
}
__device__ __forceinline__ unsigned int permhi(unsigned int A, unsigned int B) {
    return __builtin_amdgcn_perm(B, A, 0x07060302u);
}

// ---- DPP rotate-reduce over 16-lane rows (VALU pipe, zero DS ops) ----
// row_ror:n ctrl = 0x120|n; steps 1,2,4,8 give all-lanes full reduction.
template<int CTRL>
__device__ __forceinline__ float dppadd(float v) {
    int t = __builtin_amdgcn_update_dpp(0, __builtin_bit_cast(int, v),
                                        CTRL, 0xF, 0xF, true);
    return v + __builtin_bit_cast(float, t);
}
template<int CTRL>
__device__ __forceinline__ float dppmax(float v) {
    int t = __builtin_amdgcn_update_dpp(0, __builtin_bit_cast(int, v),
                                        CTRL, 0xF, 0xF, true);
    return fmaxf(v, __builtin_bit_cast(float, t));
}
__device__ __forceinline__ float rsum16(float v) {
    v = dppadd<0x121>(v); v = dppadd<0x122>(v);
    v = dppadd<0x124>(v); v = dppadd<0x128>(v);
    return v;
}
__device__ __forceinline__ float rmax16(float v) {
    v = dppmax<0x121>(v); v = dppmax<0x122>(v);
    v = dppmax<0x124>(v); v = dppmax<0x128>(v);
    return v;
}

// XOR-swizzled 64x64 bf16 LDS layout: 16B group g of row r at position g ^ (r & 7)
__device__ __forceinline__ int eoff(int r, int c) {
    return r * 64 + ((((c >> 3) ^ r) & 7) << 3) + (c & 7);
}
__device__ __forceinline__ int goff(int r, int g) {
    return r * 64 + (((g ^ r) & 7) << 3);
}

// One-shot: C^T in bf16 hi/lo, pre-swizzled into MFMA B-fragment order.
// ws shorts: hi = [0..4095], lo = [4096..8191].
// Fragment f = t*2+kk: lane's short8 at ((f*64)+lane)*8;
// element e = Ct[16t+(lane&15)][(kk*4+(lane>>4))*8+e] = corr[k][16t+(lane&15)].
__global__ void prep_corr(const float* __restrict__ corr,
                          unsigned short* __restrict__ ws) {
    const int tid  = threadIdx.x;   // 256
    const int lane = tid & 63;
    const int t    = tid >> 6;
    const int nn   = lane & 15;
    const int q    = lane >> 4;
    const int brow = 16 * t + nn;
    #pragma unroll
    for (int kk = 0; kk < 2; ++kk) {
        const int kbase = (kk * 4 + q) * 8;
        short8 H8, L8;
        #pragma unroll
        for (int e = 0; e < 8; ++e) {
            const float v = corr[(kbase + e) * 64 + brow];
            const unsigned short hh = bf16hi_sw(v);
            const unsigned short ll = bf16hi_sw(v - bf16f(hh));
            H8[e] = (short)hh;
            L8[e] = (short)ll;
        }
        const int idx = ((t * 2 + kk) * 64 + lane) * 8;
        *(short8*)&ws[idx]        = H8;
        *(short8*)&ws[4096 + idx] = L8;
    }
}

// USEWS=true : Ct B-frags from global ws (L1-hot), 1 barrier.
// USEWS=false: Ct staged in LDS, 2 barriers.
template<bool USEWS>
__global__ __launch_bounds__(256, 4)
void attn_mfma(const float* __restrict__ fi,
               const float* __restrict__ corr,
               const unsigned short* __restrict__ wsC,
               const float* __restrict__ ln_g,
               const float* __restrict__ ln_b,
               const float* __restrict__ lw,
               const float* __restrict__ lb,
               float* __restrict__ out)
{
    // 5 x 8 KB = 40960 B -> 4 blocks/CU
    __shared__ __align__(16) unsigned short sFiH[4096], sFiL[4096]; // fi rows h/l
    __shared__ __align__(16) unsigned short sFtH[4096];             // fi^T rows, hi
    // sPH/sPL: [fallback: Ct h/l] -> fiC h/l; sPH later = alpha (wave-private rows)
    __shared__ __align__(16) unsigned short sPH[4096], sPL[4096];

    const int tid  = threadIdx.x;
    const int lane = tid & 63;
    const int w    = tid >> 6;
    const int n    = lane & 15;
    const int quad = lane >> 4;
    const size_t blk = blockIdx.x;

    const short8* wCH = (const short8*)wsC;            // [f*64 + lane]
    const short8* wCL = (const short8*)(wsC + 4096);

    // ---- staging: thread owns a 4x4 tile of fi: rows R..R+3, cols C..C+3.
    // Within a wave, R spans 16w..16w+15 (wave-private rows); DPP-row = quad.
    const int C = 4 * n;
    const int R = 4 * (tid >> 4);   // = 16w + 4*quad
    float d0v[4];
    {
        const float* fb = fi + blk * 4096;
        float4 v[4];
        #pragma unroll
        for (int i = 0; i < 4; ++i)
            v[i] = *(const float4*)(fb + (R + i) * 64 + C);

        const float4 w0v = *(const float4*)&lw[C];
        #pragma unroll
        for (int i = 0; i < 4; ++i) {
            float p = v[i].x * w0v.x + v[i].y * w0v.y
                    + v[i].z * w0v.z + v[i].w * w0v.w;
            d0v[i] = rsum16(p);   // all 16 lanes of the row-group get row R+i's dot
        }

        unsigned int H01[4], H23[4], L01[4], L23[4];
        #pragma unroll
        for (int i = 0; i < 4; ++i) {
            splitpk(v[i].x, v[i].y, H01[i], L01[i]);
            splitpk(v[i].z, v[i].w, H23[i], L23[i]);
        }
        // fi rows (hi/lo), b64 each
        #pragma unroll
        for (int i = 0; i < 4; ++i) {
            uint2 H = {H01[i], H23[i]};
            uint2 L = {L01[i], L23[i]};
            *(uint2*)&sFiH[eoff(R + i, C)] = H;
            *(uint2*)&sFiL[eoff(R + i, C)] = L;
        }
        // fi^T rows (hi only): col C+j holds fi[R..R+3][C+j], packed b64
        uint2 t0 = {permlo(H01[0], H01[1]), permlo(H01[2], H01[3])};
        uint2 t1 = {permhi(H01[0], H01[1]), permhi(H01[2], H01[3])};
        uint2 t2 = {permlo(H23[0], H23[1]), permlo(H23[2], H23[3])};
        uint2 t3 = {permhi(H23[0], H23[1]), permhi(H23[2], H23[3])};
        *(uint2*)&sFtH[eoff(C + 0, R)] = t0;
        *(uint2*)&sFtH[eoff(C + 1, R)] = t1;
        *(uint2*)&sFtH[eoff(C + 2, R)] = t2;
        *(uint2*)&sFtH[eoff(C + 3, R)] = t3;
    }

    if constexpr (!USEWS) {
        // ---- fallback: stage Ct = corr^T (hi/lo) via 4x4 tiles ----
        float4 cv[4];
        #pragma unroll
        for (int i = 0; i < 4; ++i)
            cv[i] = *(const float4*)(corr + (size_t)(R + i) * 64 + C);
        unsigned int cH01[4], cH23[4], cL01[4], cL23[4];
        #pragma unroll
        for (int i = 0; i < 4; ++i) {
            splitpk(cv[i].x, cv[i].y, cH01[i], cL01[i]);
            splitpk(cv[i].z, cv[i].w, cH23[i], cL23[i]);
        }
        uint2 h0 = {permlo(cH01[0], cH01[1]), permlo(cH01[2], cH01[3])};
        uint2 h1 = {permhi(cH01[0], cH01[1]), permhi(cH01[2], cH01[3])};
        uint2 h2 = {permlo(cH23[0], cH23[1]), permlo(cH23[2], cH23[3])};
        uint2 h3 = {permhi(cH23[0], cH23[1]), permhi(cH23[2], cH23[3])};
        uint2 l0 = {permlo(cL01[0], cL01[1]), permlo(cL01[2], cL01[3])};
        uint2 l1 = {permhi(cL01[0], cL01[1]), permhi(cL01[2], cL01[3])};
        uint2 l2 = {permlo(cL23[0], cL23[1]), permlo(cL23[2], cL23[3])};
        uint2 l3 = {permhi(cL23[0], cL23[1]), permhi(cL23[2], cL23[3])};
        *(uint2*)&sPH[eoff(C + 0, R)] = h0;  *(uint2*)&sPL[eoff(C + 0, R)] = l0;
        *(uint2*)&sPH[eoff(C + 1, R)] = h1;  *(uint2*)&sPL[eoff(C + 1, R)] = l1;
        *(uint2*)&sPH[eoff(C + 2, R)] = h2;  *(uint2*)&sPL[eoff(C + 2, R)] = l2;
        *(uint2*)&sPH[eoff(C + 3, R)] = h3;  *(uint2*)&sPL[eoff(C + 3, R)] = l3;
        __syncthreads();   // bar1: sFi/sFt/Ct visible
    }

    const int arow = 16 * w + n;

    // ---- M1: fiC = fi @ C (A: own-wave sFi rows; B: Ct frags) ----
    short8 Ah[2], Al[2];
    #pragma unroll
    for (int kk = 0; kk < 2; ++kk) {
        Ah[kk] = *(const short8*)&sFiH[goff(arow, kk * 4 + quad)];
        Al[kk] = *(const short8*)&sFiL[goff(arow, kk * 4 + quad)];
    }
    floatx4 acc1[4];
    #pragma unroll
    for (int t = 0; t < 4; ++t) {
        floatx4 acc = {0.f, 0.f, 0.f, 0.f};
        #pragma unroll
        for (int kk = 0; kk < 2; ++kk) {
            short8 bh, bl;
            if constexpr (USEWS) {
                const int f = t * 2 + kk;
                bh = wCH[f * 64 + lane];
                bl = wCL[f * 64 + lane];
            } else {
                const int brow = 16 * t + n;
                bh = *(const short8*)&sPH[goff(brow, kk * 4 + quad)];
                bl = *(const short8*)&sPL[goff(brow, kk * 4 + quad)];
            }
            acc = __builtin_amdgcn_mfma_f32_16x16x32_bf16(Ah[kk], bh, acc, 0, 0, 0);
            acc = __builtin_amdgcn_mfma_f32_16x16x32_bf16(Al[kk], bh, acc, 0, 0, 0);
            acc = __builtin_amdgcn_mfma_f32_16x16x32_bf16(Ah[kk], bl, acc, 0, 0, 0);
        }
        acc1[t] = acc;
    }

    if constexpr (!USEWS) __syncthreads();   // bar2: Ct reads done before overwrite

    // fiC -> sP (wave-private rows)
    #pragma unroll
    for (int t = 0; t < 4; ++t) {
        const int col = 16 * t + n;
        const int row = 16 * w + quad * 4;
        unsigned int H01, L01, H23, L23;
        splitpk(acc1[t][0], acc1[t][1], H01, L01);
        splitpk(acc1[t][2], acc1[t][3], H23, L23);
        sPH[eoff(row + 0, col)] = (unsigned short)H01;
        sPH[eoff(row + 1, col)] = (unsigned short)(H01 >> 16);
        sPH[eoff(row + 2, col)] = (unsigned short)H23;
        sPH[eoff(row + 3, col)] = (unsigned short)(H23 >> 16);
        sPL[eoff(row + 0, col)] = (unsigned short)L01;
        sPL[eoff(row + 1, col)] = (unsigned short)(L01 >> 16);
        sPL[eoff(row + 2, col)] = (unsigned short)L23;
        sPL[eoff(row + 3, col)] = (unsigned short)(L23 >> 16);
    }

    if constexpr (USEWS) __syncthreads();   // single barrier: staging visible

    // ---- M2: beta = fiC @ fi^T (A: own sP rows; B: sFi rows, all waves) ----
    short8 PAh[2], PAl[2];
    #pragma unroll
    for (int kk = 0; kk < 2; ++kk) {
        PAh[kk] = *(const short8*)&sPH[goff(arow, kk * 4 + quad)];
        PAl[kk] = *(const short8*)&sPL[goff(arow, kk * 4 + quad)];
    }
    floatx4 acc2[4];
    #pragma unroll
    for (int t = 0; t < 4; ++t) {
        floatx4 acc = {0.f, 0.f, 0.f, 0.f};
        const int brow = 16 * t + n;
        #pragma unroll
        for (int kk = 0; kk < 2; ++kk) {
            short8 bh = *(const short8*)&sFiH[goff(brow, kk * 4 + quad)];
            short8 bl = *(const short8*)&sFiL[goff(brow, kk * 4 + quad)];
            acc = __builtin_amdgcn_mfma_f32_16x16x32_bf16(PAh[kk], bh, acc, 0, 0, 0);
            acc = __builtin_amdgcn_mfma_f32_16x16x32_bf16(PAl[kk], bh, acc, 0, 0, 0);
            acc = __builtin_amdgcn_mfma_f32_16x16x32_bf16(PAh[kk], bl, acc, 0, 0, 0);
        }
        acc2[t] = acc;
    }

    // ---- masked softmax, UNNORMALIZED (LN is scale-invariant) ----
    #pragma unroll
    for (int reg = 0; reg < 4; ++reg) {
        const int row = 16 * w + quad * 4 + reg;
        float x[4];
        #pragma unroll
        for (int t = 0; t < 4; ++t) {
            x[t] = acc2[t][reg];
            if (row == 16 * t + n) x[t] = NEG_INF_V;
        }
        float m = fmaxf(fmaxf(x[0], x[1]), fmaxf(x[2], x[3]));
        m = rmax16(m);
        #pragma unroll
        for (int t = 0; t < 4; ++t) x[t] = __expf(x[t] - m);   // <= 1
        const unsigned int A01 = pk2(x[0], x[1]);
        const unsigned int A23 = pk2(x[2], x[3]);
        sPH[eoff(row, 0 + n)]  = (unsigned short)A01;   // alpha reuses sPH (own rows)
        sPH[eoff(row, 16 + n)] = (unsigned short)(A01 >> 16);
        sPH[eoff(row, 32 + n)] = (unsigned short)A23;
        sPH[eoff(row, 48 + n)] = (unsigned short)(A23 >> 16);
    }

    // ---- M3: vi_unnorm = exp(beta-m) @ fi (hi-only single pass) ----
    short8 AAh[2];
    #pragma unroll
    for (int kk = 0; kk < 2; ++kk)
        AAh[kk] = *(const short8*)&sPH[goff(arow, kk * 4 + quad)];
    floatx4 acc3[4];
    #pragma unroll
    for (int t = 0; t < 4; ++t) {
        floatx4 acc = {0.f, 0.f, 0.f, 0.f};
        const int brow = 16 * t + n;
        #pragma unroll
        for (int kk = 0; kk < 2; ++kk) {
            short8 bh = *(const short8*)&sFtH[goff(brow, kk * 4 + quad)];
            acc = __builtin_amdgcn_mfma_f32_16x16x32_bf16(AAh[kk], bh, acc, 0, 0, 0);
        }
        acc3[t] = acc;
    }

    // ---- LN + ReLU + final dot + sigmoid ----
    float gv[4], bv[4], w1v[4];
    #pragma unroll
    for (int t = 0; t < 4; ++t) {
        gv[t]  = ln_g[16 * t + n];
        bv[t]  = ln_b[16 * t + n];
        w1v[t] = lw[64 + 16 * t + n];
    }
    const float bias = lb[0];
    float res[4];
    #pragma unroll
    for (int reg = 0; reg < 4; ++reg) {
        float s  = acc3[0][reg] + acc3[1][reg] + acc3[2][reg] + acc3[3][reg];
        float s2 = acc3[0][reg] * acc3[0][reg] + acc3[1][reg] * acc3[1][reg]
                 + acc3[2][reg] * acc3[2][reg] + acc3[3][reg] * acc3[3][reg];
        s  = rsum16(s);
        s2 = rsum16(s2);
        const float mu  = s * (1.0f / 64.0f);
        const float var = s2 * (1.0f / 64.0f) - mu * mu;
        const float rstd = __builtin_amdgcn_rsqf(var + LN_EPS);
        float dotp = 0.f;
        #pragma unroll
        for (int t = 0; t < 4; ++t) {
            float lnv = (acc3[t][reg] - mu) * rstd * gv[t] + bv[t];
            lnv = fmaxf(lnv, 0.f);
            dotp += lnv * w1v[t];
        }
        dotp = rsum16(dotp);
        // d0 of row 16w+quad*4+reg is lane-local: staging row-group == quad
        res[reg] = __builtin_amdgcn_rcpf(1.0f + __expf(-(dotp + d0v[reg] + bias)));
    }
    if (n == 0) {
        float4 o = {res[0], res[1], res[2], res[3]};
        *(float4*)&out[blk * 64 + 16 * w + quad * 4] = o;
    }
}

extern "C" void kernel_launch(void* const* d_in, const int* in_sizes, int n_in,
                              void* d_out, int out_size, void* d_ws, size_t ws_size,
                              hipStream_t stream) {
    const float* fi   = (const float*)d_in[0];
    const float* corr = (const float*)d_in[1];
    const float* g    = (const float*)d_in[2];
    const float* b    = (const float*)d_in[3];
    const float* lw   = (const float*)d_in[4];
    const float* lb   = (const float*)d_in[5];
    float* out        = (float*)d_out;

    const int B = in_sizes[0] / 4096;

    if (d_ws != nullptr && ws_size >= 16384) {
        unsigned short* wsC = (unsigned short*)d_ws;   // 16 KB used
        hipLaunchKernelGGL(prep_corr, dim3(1), dim3(256), 0, stream, corr, wsC);
        hipLaunchKernelGGL(HIP_KERNEL_NAME(attn_mfma<true>), dim3(B), dim3(256), 0,
                           stream, fi, corr, wsC, g, b, lw, lb, out);
    } else {
        hipLaunchKernelGGL(HIP_KERNEL_NAME(attn_mfma<false>), dim3(B), dim3(256), 0,
                           stream, fi, corr, (const unsigned short*)nullptr,
                           g, b, lw, lb, out);
    }
}